// Round 11
// baseline (315.643 us; speedup 1.0000x reference)
//
#include <hip/hip_runtime.h>

#define DD 128
#define BSHIFT 7
#define BROWS 128
#define MS_TILE 4096
#define MS_EPT 8       // edges per thread at 512 threads
#define STAGE_CAP 6144 // bucket_csr LDS stage capacity (>= cap)
#define MSB_LDS 43008  // multisplit LDS bytes (5*2048 + 4096*8)

typedef __attribute__((ext_vector_type(8))) short short8;
typedef __attribute__((ext_vector_type(4))) float f32x4;
typedef unsigned short u16;
typedef unsigned int u32;

__device__ __forceinline__ u16 f2bf(float f) {
  u32 u = __builtin_bit_cast(u32, f);
  u += 0x7fffu + ((u >> 16) & 1u);
  return (u16)(u >> 16);
}
__device__ __forceinline__ float bf2f(u16 s) {
  u32 u = ((u32)s) << 16;
  return __builtin_bit_cast(float, u);
}
__device__ __forceinline__ float f16val(u32 cv) {
  return (float)__builtin_bit_cast(_Float16, (u16)(cv & 0xffffu));
}
__device__ __forceinline__ float sigmoidf_(float v) { return 1.f / (1.f + __expf(-v)); }
__device__ __forceinline__ float tanhf_(float v) {
  float e = __expf(-2.f * v);
  return (1.f - e) / (1.f + e);
}

struct WPtrs { const float* w[10]; };

// Composite weights: Wc[m] = W4 @ {Wu1,Wr1,Wo1}[m]  (fp32), plus combined biases:
// bzc = bu1+bu2+b4@Wu1 ; brc = br1+br2+b4@Wr1 ; boc = bo1+b4@Wo1
__global__ __launch_bounds__(256) void compose(const float* __restrict__ W4,
                                               const float* __restrict__ Wu1,
                                               const float* __restrict__ Wr1,
                                               const float* __restrict__ Wo1,
                                               const float* __restrict__ b4,
                                               const float* __restrict__ bu1,
                                               const float* __restrict__ bu2,
                                               const float* __restrict__ br1,
                                               const float* __restrict__ br2,
                                               const float* __restrict__ bo1,
                                               float* __restrict__ Wc, float* __restrict__ bc) {
  const int mat = blockIdx.x >> 3;
  const int rowg = blockIdx.x & 7;
  const float* Ws = (mat == 0) ? Wu1 : (mat == 1) ? Wr1 : Wo1;
  float* out = Wc + (size_t)mat * 16384;
  for (int i = threadIdx.x; i < 2048; i += 256) {
    int k = rowg * 16 + (i >> 7);
    int c = i & 127;
    float s = 0.f;
#pragma unroll 8
    for (int j = 0; j < 128; ++j) s += W4[k * 128 + j] * Ws[j * 128 + c];
    out[k * 128 + c] = s;
  }
  if (rowg == 0 && threadIdx.x < 128) {
    int c = threadIdx.x;
    float s = 0.f;
    for (int k = 0; k < 128; ++k) s += b4[k] * Ws[k * 128 + c];
    float base = (mat == 0) ? (bu1[c] + bu2[c]) : (mat == 1) ? (br1[c] + br2[c]) : bo1[c];
    bc[mat * 128 + c] = base + s;
  }
}

// Pack W [k][n] (row-major fp32, 128x128) into fragment-major bf16:
// Bp[((ks*8+nt)*64 + lane)*8 + e] = bf16( W[ks*32 + (lane>>4)*8 + e][(lane&15) + nt*16] )
__global__ void pack_weights(WPtrs wp, u16* __restrict__ bp) {
  const float* W = wp.w[blockIdx.x];
  u16* out = bp + (size_t)blockIdx.x * 16384;
  for (int o = threadIdx.x; o < 16384; o += blockDim.x) {
    int e = o & 7, lane = (o >> 3) & 63, nt = (o >> 9) & 7, ks = o >> 12;
    int k = ks * 32 + (lane >> 4) * 8 + e;
    int c = (lane & 15) + nt * 16;
    out[o] = f2bf(W[k * DD + c]);
  }
}

// Grid-partition fused kernel: blocks [0, msBlocks) run the edge multisplit;
// blocks [msBlocks, ...) run the first fused 2-layer MLP (fp32 input).
// The two parts are fully independent; LDS is aliased through one buffer.
__global__ __launch_bounds__(512) void ms_mlp_fused(
    const int* __restrict__ rows, const int* __restrict__ cols, const float* __restrict__ vals,
    int* __restrict__ cursor, uint2* __restrict__ recs, int E, int NB, int cap, int msBlocks,
    const float* __restrict__ Ain, const u16* __restrict__ W1p, const float* __restrict__ b1,
    const u16* __restrict__ W2p, const float* __restrict__ b2, u16* __restrict__ outB, int n) {
  __shared__ __align__(16) char smraw[MSB_LDS];
  const int t = threadIdx.x;
  if (blockIdx.x < msBlocks) {
    // ---------------- multisplit part ----------------
    u32* hist = (u32*)smraw;
    u32* scan_tmp = (u32*)(smraw + 2048);
    u32* hbase = (u32*)(smraw + 4096);
    int* gbase = (int*)(smraw + 6144);
    u32* rankc = (u32*)(smraw + 8192);
    uint2* stage = (uint2*)(smraw + 10240);
    const int tile0 = blockIdx.x * MS_TILE;
    hist[t] = 0;
    rankc[t] = 0;
    __syncthreads();
    int myb[MS_EPT];
    u32 mycv[MS_EPT], myrow[MS_EPT];
#pragma unroll
    for (int j = 0; j < MS_EPT; ++j) {
      int e = tile0 + j * 512 + t;
      if (e < E) {
        int r = rows[e];
        int b = r >> BSHIFT;
        myb[j] = b;
        myrow[j] = (u32)r;
        _Float16 hf = (_Float16)vals[e];
        mycv[j] = ((u32)cols[e] << 16) | (u32)__builtin_bit_cast(u16, hf);
        atomicAdd(&hist[b], 1u);
      } else {
        myb[j] = -1;
      }
    }
    __syncthreads();
    u32 v = hist[t];
    scan_tmp[t] = v;
    __syncthreads();
    for (int o = 1; o < 512; o <<= 1) {
      u32 x = (t >= o) ? scan_tmp[t - o] : 0;
      __syncthreads();
      scan_tmp[t] += x;
      __syncthreads();
    }
    hbase[t] = scan_tmp[t] - v;
    if (t < NB && v > 0) gbase[t] = atomicAdd(&cursor[t], (int)v);
    __syncthreads();
#pragma unroll
    for (int j = 0; j < MS_EPT; ++j) {
      if (myb[j] >= 0) {
        u32 rk = atomicAdd(&rankc[myb[j]], 1u);
        stage[hbase[myb[j]] + rk].x = mycv[j];
        stage[hbase[myb[j]] + rk].y = myrow[j];
      }
    }
    __syncthreads();
    int cnt = E - tile0;
    cnt = cnt < MS_TILE ? cnt : MS_TILE;
    for (int k = t; k < cnt; k += 512) {
      uint2 rec = stage[k];
      int b = (int)(rec.y >> BSHIFT);
      int off = gbase[b] + (k - (int)hbase[b]);
      if (off < cap) recs[(size_t)b * cap + off] = rec;
    }
  } else {
    // ---------------- first MLP part (64 rows/block, 8 waves) ----------------
    u16(*sm)[136] = (u16(*)[136])smraw;
    const int lane = t & 63;
    const int wid = t >> 6;            // 0..7
    const int tile = wid >> 1;         // 0..3 (16-row tile)
    const int c = wid & 1;             // col-half
    const int row0 = (blockIdx.x - msBlocks) * 64 + tile * 16;
    const int ar = lane & 15, ak = (lane >> 4) * 8;
    const int crow = 4 * (lane >> 4), ccol = lane & 15;

    f32x4 acc[4];
#pragma unroll
    for (int q = 0; q < 4; ++q) acc[q] = f32x4{0.f, 0.f, 0.f, 0.f};
#pragma unroll
    for (int ks = 0; ks < 4; ++ks) {
      int r = row0 + ar;
      r = r < n ? r : n - 1;
      const float* Ap = Ain + (size_t)r * DD + ks * 32 + ak;
      float4 f0 = *reinterpret_cast<const float4*>(Ap);
      float4 f1 = *reinterpret_cast<const float4*>(Ap + 4);
      short8 a;
      a[0] = (short)f2bf(f0.x); a[1] = (short)f2bf(f0.y);
      a[2] = (short)f2bf(f0.z); a[3] = (short)f2bf(f0.w);
      a[4] = (short)f2bf(f1.x); a[5] = (short)f2bf(f1.y);
      a[6] = (short)f2bf(f1.z); a[7] = (short)f2bf(f1.w);
#pragma unroll
      for (int nt4 = 0; nt4 < 4; ++nt4) {
        int nt = c * 4 + nt4;
        short8 bfr = *reinterpret_cast<const short8*>(W1p + (((ks * 8 + nt) * 64 + lane) * 8));
        acc[nt4] = __builtin_amdgcn_mfma_f32_16x16x32_bf16(a, bfr, acc[nt4], 0, 0, 0);
      }
    }
#pragma unroll
    for (int nt4 = 0; nt4 < 4; ++nt4) {
      int col = (c * 4 + nt4) * 16 + ccol;
      float bsv = b1[col];
#pragma unroll
      for (int e = 0; e < 4; ++e) {
        float v = acc[nt4][e] + bsv;
        v = v > 0.f ? v : 0.f;
        sm[tile * 16 + crow + e][col] = f2bf(v);
      }
    }
    __syncthreads();
    f32x4 acc2[4];
#pragma unroll
    for (int q = 0; q < 4; ++q) acc2[q] = f32x4{0.f, 0.f, 0.f, 0.f};
#pragma unroll
    for (int ks = 0; ks < 4; ++ks) {
      short8 a2 = *reinterpret_cast<const short8*>(&sm[tile * 16 + ar][ks * 32 + ak]);
#pragma unroll
      for (int nt4 = 0; nt4 < 4; ++nt4) {
        int nt = c * 4 + nt4;
        short8 bfr = *reinterpret_cast<const short8*>(W2p + (((ks * 8 + nt) * 64 + lane) * 8));
        acc2[nt4] = __builtin_amdgcn_mfma_f32_16x16x32_bf16(a2, bfr, acc2[nt4], 0, 0, 0);
      }
    }
#pragma unroll
    for (int nt4 = 0; nt4 < 4; ++nt4) {
      int col = (c * 4 + nt4) * 16 + ccol;
      float bsv = b2[col];
#pragma unroll
      for (int e = 0; e < 4; ++e) {
        int r = row0 + crow + e;
        if (r < n) outB[(size_t)r * DD + col] = f2bf(acc2[nt4][e] + bsv);
      }
    }
  }
}

// Per-bucket CSR: row-sort the bucket's records in LDS, write coalesced 4B records
// plus per-row start/count. One block per bucket.
__global__ __launch_bounds__(512) void bucket_csr(const uint2* __restrict__ recs,
                                                  const int* __restrict__ cursor,
                                                  u32* __restrict__ recs2,
                                                  int* __restrict__ rowstart,
                                                  int* __restrict__ rowcnt, int n, int cap) {
  __shared__ int hist[BROWS];
  __shared__ int sc[BROWS];
  __shared__ int hbase[BROWS];
  __shared__ u32 rank[BROWS];
  __shared__ u32 stage[STAGE_CAP];
  const int t = threadIdx.x;
  const int b = blockIdx.x;
  int cnt = cursor[b];
  cnt = cnt < cap ? cnt : cap;
  const uint2* rb = recs + (size_t)b * cap;
  if (t < BROWS) { hist[t] = 0; rank[t] = 0; }
  __syncthreads();
  for (int i = t; i < cnt; i += 512) atomicAdd(&hist[rb[i].y & (BROWS - 1)], 1);
  __syncthreads();
  if (t < BROWS) sc[t] = hist[t];
  __syncthreads();
  for (int o = 1; o < BROWS; o <<= 1) {
    int x = (t >= o && t < BROWS) ? sc[t - o] : 0;
    __syncthreads();
    if (t < BROWS) sc[t] += x;
    __syncthreads();
  }
  if (t < BROWS) {
    hbase[t] = sc[t] - hist[t];
    int r = (b << BSHIFT) + t;
    if (r < n) {
      rowstart[r] = b * cap + hbase[t];
      rowcnt[r] = hist[t];
    }
  }
  __syncthreads();
  for (int i = t; i < cnt; i += 512) {
    uint2 rec = rb[i];
    int lr = (int)(rec.y & (BROWS - 1));
    u32 p = atomicAdd(&rank[lr], 1u);
    stage[hbase[lr] + p] = rec.x;
  }
  __syncthreads();
  u32* ob = recs2 + (size_t)b * cap;
  for (int i = t; i < cnt; i += 512) ob[i] = stage[i];
}

// wave per row; half-wave edge pairing: lanes 0-31 even edges, 32-63 odd edges.
__global__ void spmm_agg(const int* __restrict__ rowstart, const int* __restrict__ rowcnt,
                         const u32* __restrict__ recs2, const u16* __restrict__ xb,
                         u16* __restrict__ aggb, int n) {
  int row = blockIdx.x * 4 + (threadIdx.x >> 6);
  int lane = threadIdx.x & 63;
  if (row >= n) return;
  const int s = rowstart[row];
  const int cnt = rowcnt[row];
  const int hi = lane >> 5;
  const int l32 = lane & 31;
  float a0 = 0.f, a1 = 0.f, a2 = 0.f, a3 = 0.f;
  int j = 0;
#define SPMM_PAIR(P)                                                                   \
  {                                                                                    \
    u32 pk0 = recs2[s + j + 2 * (P)];                                                  \
    u32 pk1 = recs2[s + j + 2 * (P) + 1];                                              \
    u32 pk = hi ? pk1 : pk0;                                                           \
    uint2 xv = *(reinterpret_cast<const uint2*>(xb + (size_t)(pk >> 16) * DD) + l32);  \
    float vv = f16val(pk);                                                             \
    a0 += vv * bf2f((u16)(xv.x & 0xffffu));                                            \
    a1 += vv * bf2f((u16)(xv.x >> 16));                                                \
    a2 += vv * bf2f((u16)(xv.y & 0xffffu));                                            \
    a3 += vv * bf2f((u16)(xv.y >> 16));                                                \
  }
  for (; j + 15 < cnt; j += 16) {
    SPMM_PAIR(0) SPMM_PAIR(1) SPMM_PAIR(2) SPMM_PAIR(3)
    SPMM_PAIR(4) SPMM_PAIR(5) SPMM_PAIR(6) SPMM_PAIR(7)
  }
  for (; j + 1 < cnt; j += 2) { SPMM_PAIR(0) }
  if (j < cnt) {
    u32 pk0 = recs2[s + j];
    uint2 xv = *(reinterpret_cast<const uint2*>(xb + (size_t)(pk0 >> 16) * DD) + l32);
    float vv = hi ? 0.f : f16val(pk0);
    a0 += vv * bf2f((u16)(xv.x & 0xffffu));
    a1 += vv * bf2f((u16)(xv.x >> 16));
    a2 += vv * bf2f((u16)(xv.y & 0xffffu));
    a3 += vv * bf2f((u16)(xv.y >> 16));
  }
#undef SPMM_PAIR
  a0 += __shfl_xor(a0, 32, 64);
  a1 += __shfl_xor(a1, 32, 64);
  a2 += __shfl_xor(a2, 32, 64);
  a3 += __shfl_xor(a3, 32, 64);
  if (!hi) {
    uint2 o;
    o.x = ((u32)f2bf(a1) << 16) | (u32)f2bf(a0);
    o.y = ((u32)f2bf(a3) << 16) | (u32)f2bf(a2);
    *reinterpret_cast<uint2*>(aggb + (size_t)row * DD + l32 * 4) = o;
  }
}

// Second-MLP + gates + final with the W4-composite trick (out eliminated):
//   t2  = relu(agg@W3+b3)                      -> LDS
//   z   = sig(t2@Wu1' + x@Wu2 + bzc)
//   r   = sig(t2@Wr1' + x@Wr2 + brc)
//   oi  = t2@Wo1' + boc + (r*x)@Wo2 + bo2      (rx via LDS)
//   result = (1-z)*x + z*tanh(oi)              -> fp32 d_out
__global__ __launch_bounds__(256) void gates_final2(
    const u16* __restrict__ Agg, const u16* __restrict__ Ax, const u16* __restrict__ W3p,
    const float* __restrict__ b3, const u16* __restrict__ Wu1p, const u16* __restrict__ Wu2p,
    const u16* __restrict__ Wr1p, const u16* __restrict__ Wr2p, const u16* __restrict__ Wo1p,
    const u16* __restrict__ Wo2p, const float* __restrict__ bzc, const float* __restrict__ brc,
    const float* __restrict__ boc, const float* __restrict__ bo2, float* __restrict__ out,
    int n) {
  __shared__ u16 sm[32][136];  // reused: t2 tile -> rx tile
  const int lane = threadIdx.x & 63;
  const int wid = threadIdx.x >> 6;
  const int m = wid >> 1, c = wid & 1;
  const int row0 = blockIdx.x * 32 + m * 16;
  const int ar = lane & 15, ak = (lane >> 4) * 8;
  const int crow = 4 * (lane >> 4), ccol = lane & 15;

  // phase 1: t2 = relu(agg@W3 + b3) -> sm
  f32x4 acc[4];
#pragma unroll
  for (int q = 0; q < 4; ++q) acc[q] = f32x4{0.f, 0.f, 0.f, 0.f};
#pragma unroll
  for (int ks = 0; ks < 4; ++ks) {
    int r = row0 + ar;
    r = r < n ? r : n - 1;
    short8 a = *reinterpret_cast<const short8*>(Agg + (size_t)r * DD + ks * 32 + ak);
#pragma unroll
    for (int nt4 = 0; nt4 < 4; ++nt4) {
      int nt = c * 4 + nt4;
      short8 bfr = *reinterpret_cast<const short8*>(W3p + (((ks * 8 + nt) * 64 + lane) * 8));
      acc[nt4] = __builtin_amdgcn_mfma_f32_16x16x32_bf16(a, bfr, acc[nt4], 0, 0, 0);
    }
  }
#pragma unroll
  for (int nt4 = 0; nt4 < 4; ++nt4) {
    int col = (c * 4 + nt4) * 16 + ccol;
    float bsv = b3[col];
#pragma unroll
    for (int e = 0; e < 4; ++e) {
      float v = acc[nt4][e] + bsv;
      v = v > 0.f ? v : 0.f;
      sm[m * 16 + crow + e][col] = f2bf(v);
    }
  }
  __syncthreads();

  // phase 2: gates with composite weights. A-operands: t2 from LDS, x from global.
  f32x4 aZ[4], aR[4], aO[4];
#pragma unroll
  for (int q = 0; q < 4; ++q) {
    aZ[q] = f32x4{0.f, 0.f, 0.f, 0.f};
    aR[q] = f32x4{0.f, 0.f, 0.f, 0.f};
    aO[q] = f32x4{0.f, 0.f, 0.f, 0.f};
  }
#pragma unroll
  for (int ks = 0; ks < 4; ++ks) {
    int r = row0 + ar;
    r = r < n ? r : n - 1;
    short8 ao = *reinterpret_cast<const short8*>(&sm[m * 16 + ar][ks * 32 + ak]);
    short8 ax = *reinterpret_cast<const short8*>(Ax + (size_t)r * DD + ks * 32 + ak);
#pragma unroll
    for (int nt4 = 0; nt4 < 4; ++nt4) {
      int nt = c * 4 + nt4;
      size_t bo = (size_t)(((ks * 8 + nt) * 64 + lane) * 8);
      short8 b1 = *reinterpret_cast<const short8*>(Wu1p + bo);
      short8 b2 = *reinterpret_cast<const short8*>(Wu2p + bo);
      short8 b3f = *reinterpret_cast<const short8*>(Wr1p + bo);
      short8 b4f = *reinterpret_cast<const short8*>(Wr2p + bo);
      short8 b5 = *reinterpret_cast<const short8*>(Wo1p + bo);
      aZ[nt4] = __builtin_amdgcn_mfma_f32_16x16x32_bf16(ao, b1, aZ[nt4], 0, 0, 0);
      aZ[nt4] = __builtin_amdgcn_mfma_f32_16x16x32_bf16(ax, b2, aZ[nt4], 0, 0, 0);
      aR[nt4] = __builtin_amdgcn_mfma_f32_16x16x32_bf16(ao, b3f, aR[nt4], 0, 0, 0);
      aR[nt4] = __builtin_amdgcn_mfma_f32_16x16x32_bf16(ax, b4f, aR[nt4], 0, 0, 0);
      aO[nt4] = __builtin_amdgcn_mfma_f32_16x16x32_bf16(ao, b5, aO[nt4], 0, 0, 0);
    }
  }
  __syncthreads();  // done reading t2 before overwriting sm with rx
#pragma unroll
  for (int nt4 = 0; nt4 < 4; ++nt4) {
    int col = (c * 4 + nt4) * 16 + ccol;
    float bz = bzc[col];
    float br_ = brc[col];
    float bo_ = boc[col];
#pragma unroll
    for (int e = 0; e < 4; ++e) {
      int r = row0 + crow + e;
      float z = sigmoidf_(aZ[nt4][e] + bz);
      float rr = sigmoidf_(aR[nt4][e] + br_);
      aZ[nt4][e] = z;
      aO[nt4][e] = aO[nt4][e] + bo_;
      float xv = 0.f;
      if (r < n) xv = bf2f(Ax[(size_t)r * DD + col]);
      sm[m * 16 + crow + e][col] = f2bf(rr * xv);
    }
  }
  __syncthreads();

  // phase 3: rx@Wo2, final epilogue -> fp32 out
  f32x4 acc2[4];
#pragma unroll
  for (int q = 0; q < 4; ++q) acc2[q] = f32x4{0.f, 0.f, 0.f, 0.f};
#pragma unroll
  for (int ks = 0; ks < 4; ++ks) {
    short8 a2 = *reinterpret_cast<const short8*>(&sm[m * 16 + ar][ks * 32 + ak]);
#pragma unroll
    for (int nt4 = 0; nt4 < 4; ++nt4) {
      int nt = c * 4 + nt4;
      short8 bfr = *reinterpret_cast<const short8*>(Wo2p + (((ks * 8 + nt) * 64 + lane) * 8));
      acc2[nt4] = __builtin_amdgcn_mfma_f32_16x16x32_bf16(a2, bfr, acc2[nt4], 0, 0, 0);
    }
  }
#pragma unroll
  for (int nt4 = 0; nt4 < 4; ++nt4) {
    int col = (c * 4 + nt4) * 16 + ccol;
    float bo2v = bo2[col];
#pragma unroll
    for (int e = 0; e < 4; ++e) {
      int r = row0 + crow + e;
      if (r < n) {
        size_t idx = (size_t)r * DD + col;
        float oi = acc2[nt4][e] + bo2v + aO[nt4][e];
        float h = tanhf_(oi);
        float z = aZ[nt4][e];
        float xv = bf2f(Ax[idx]);
        out[idx] = (1.f - z) * xv + z * h;
      }
    }
  }
}

extern "C" void kernel_launch(void* const* d_in, const int* in_sizes, int n_in,
                              void* d_out, int out_size, void* d_ws, size_t ws_size,
                              hipStream_t stream) {
  const int n = in_sizes[0] / DD;  // 50000
  const int E = in_sizes[1];       // 1.6M
  const float* x_in = (const float*)d_in[0];
  const int* rows = (const int*)d_in[1];
  const int* cols = (const int*)d_in[2];
  const float* vals = (const float*)d_in[3];
  const float* Wm[10];
  const float* Bm[10];
  for (int i = 0; i < 10; ++i) {
    Wm[i] = (const float*)d_in[4 + 2 * i];
    Bm[i] = (const float*)d_in[5 + 2 * i];
  }

  const int NB = (n + BROWS - 1) >> BSHIFT;           // 391
  int cap = (((E / NB) * 5) / 4 + 511) & ~511;        // ~5120, 16-sigma slack
  cap = cap < STAGE_CAP ? cap : STAGE_CAP;

  char* base = (char*)d_ws;
  size_t off = 0;
  auto alloc = [&](size_t bytes) -> char* {
    char* p = base + off;
    off += (bytes + 255) & ~(size_t)255;
    return p;
  };
  u16* wpack = (u16*)alloc((size_t)9 * 16384 * 2);
  float* Wc = (float*)alloc((size_t)3 * 16384 * 4);
  float* bc = (float*)alloc((size_t)3 * 128 * 4);
  u16* x_b = (u16*)alloc((size_t)n * DD * 2);
  u16* agg_b = (u16*)alloc((size_t)n * DD * 2);
  int* cursor = (int*)alloc((size_t)NB * 4);
  int* rowstart = (int*)alloc((size_t)n * 4);
  int* rowcnt = (int*)alloc((size_t)n * 4);
  uint2* recs = (uint2*)alloc((size_t)NB * cap * 8);
  u32* recs2 = (u32*)alloc((size_t)NB * cap * 4);
  (void)ws_size;
  (void)n_in;
  (void)out_size;

  hipMemsetAsync(cursor, 0, (size_t)NB * 4, stream);
  // composite weights Wu1' = W4@Wu1 etc. + combined biases
  compose<<<24, 256, 0, stream>>>(Wm[3], Wm[4], Wm[6], Wm[8], Bm[3], Bm[4], Bm[5], Bm[6], Bm[7],
                                  Bm[8], Wc, bc);
  // pack 9 weights: W1,W2,W3, Wu1', Wu2, Wr1', Wr2, Wo1', Wo2
  WPtrs wp;
  wp.w[0] = Wm[0]; wp.w[1] = Wm[1]; wp.w[2] = Wm[2];
  wp.w[3] = Wc + 0; wp.w[4] = Wm[5]; wp.w[5] = Wc + 16384;
  wp.w[6] = Wm[7]; wp.w[7] = Wc + 32768; wp.w[8] = Wm[9];
  wp.w[9] = Wm[9];
  pack_weights<<<9, 256, 0, stream>>>(wp, wpack);
  // fused: multisplit (blocks 0..msB) || first MLP (blocks msB..)
  const int msB = (E + MS_TILE - 1) / MS_TILE;    // 391
  const int mlpB = (n + 63) / 64;                 // 782
  ms_mlp_fused<<<msB + mlpB, 512, 0, stream>>>(rows, cols, vals, cursor, recs, E, NB, cap, msB,
                                               x_in, wpack + 0 * 16384, Bm[0],
                                               wpack + 1 * 16384, Bm[1], x_b, n);
  // row-sort each bucket in LDS -> per-row CSR with coalesced writes
  bucket_csr<<<NB, 512, 0, stream>>>(recs, cursor, recs2, rowstart, rowcnt, n, cap);
  // agg = segment_sum(vals * x[cols], rows)  (half-wave paired gather)
  spmm_agg<<<(n + 3) / 4, 256, 0, stream>>>(rowstart, rowcnt, recs2, x_b, agg_b, n);
  // second MLP + gates + final, W4 composited away
  gates_final2<<<(n + 31) / 32, 256, 0, stream>>>(
      agg_b, x_b, wpack + 2 * 16384, Bm[2], wpack + 3 * 16384, wpack + 4 * 16384,
      wpack + 5 * 16384, wpack + 6 * 16384, wpack + 7 * 16384, wpack + 8 * 16384, bc + 0,
      bc + 128, bc + 256, Bm[9], (float*)d_out, n);
}

// Round 12
// 287.498 us; speedup vs baseline: 1.0979x; 1.0979x over previous
//
#include <hip/hip_runtime.h>

#define DD 128
#define BSHIFT 7
#define BROWS 128
#define MS_TILE 4096
#define MS_EPT 8       // edges per thread at 512 threads
#define STAGE_CAP 6144 // bucket_csr LDS stage capacity (>= cap)

typedef __attribute__((ext_vector_type(8))) short short8;
typedef __attribute__((ext_vector_type(4))) float f32x4;
typedef unsigned short u16;
typedef unsigned int u32;

__device__ __forceinline__ u16 f2bf(float f) {
  u32 u = __builtin_bit_cast(u32, f);
  u += 0x7fffu + ((u >> 16) & 1u);
  return (u16)(u >> 16);
}
__device__ __forceinline__ float bf2f(u16 s) {
  u32 u = ((u32)s) << 16;
  return __builtin_bit_cast(float, u);
}
__device__ __forceinline__ float f16val(u32 cv) {
  return (float)__builtin_bit_cast(_Float16, (u16)(cv & 0xffffu));
}
__device__ __forceinline__ float sigmoidf_(float v) { return 1.f / (1.f + __expf(-v)); }
__device__ __forceinline__ float tanhf_(float v) {
  float e = __expf(-2.f * v);
  return (1.f - e) / (1.f + e);
}

struct WPtrs { const float* w[10]; };

// Pack W [k][n] (row-major fp32, 128x128) into fragment-major bf16:
// Bp[((ks*8+nt)*64 + lane)*8 + e] = bf16( W[ks*32 + (lane>>4)*8 + e][(lane&15) + nt*16] )
__global__ void pack_weights(WPtrs wp, u16* __restrict__ bp) {
  const float* W = wp.w[blockIdx.x];
  u16* out = bp + (size_t)blockIdx.x * 16384;
  for (int o = threadIdx.x; o < 16384; o += blockDim.x) {
    int e = o & 7, lane = (o >> 3) & 63, nt = (o >> 9) & 7, ks = o >> 12;
    int k = ks * 32 + (lane >> 4) * 8 + e;
    int c = (lane & 15) + nt * 16;
    out[o] = f2bf(W[k * DD + c]);
  }
}

// LDS-staged multisplit: bucket edges by row>>BSHIFT into per-bucket spans of recs.
// rec = (col<<16 | fp16(val), row). Writes are contiguous per (tile,bucket) group.
__global__ __launch_bounds__(512) void multisplit(const int* __restrict__ rows,
                                                  const int* __restrict__ cols,
                                                  const float* __restrict__ vals,
                                                  int* __restrict__ cursor,
                                                  uint2* __restrict__ recs,
                                                  int E, int NB, int cap) {
  __shared__ u32 hist[512];
  __shared__ u32 scan_tmp[512];
  __shared__ u32 hbase[512];
  __shared__ int gbase[512];
  __shared__ u32 rankc[512];
  __shared__ uint2 stage[MS_TILE];
  const int t = threadIdx.x;
  const int tile0 = blockIdx.x * MS_TILE;
  hist[t] = 0;
  rankc[t] = 0;
  __syncthreads();
  int myb[MS_EPT];
  u32 mycv[MS_EPT], myrow[MS_EPT];
#pragma unroll
  for (int j = 0; j < MS_EPT; ++j) {
    int e = tile0 + j * 512 + t;
    if (e < E) {
      int r = rows[e];
      int b = r >> BSHIFT;
      myb[j] = b;
      myrow[j] = (u32)r;
      _Float16 hf = (_Float16)vals[e];
      mycv[j] = ((u32)cols[e] << 16) | (u32)__builtin_bit_cast(u16, hf);
      atomicAdd(&hist[b], 1u);
    } else {
      myb[j] = -1;
    }
  }
  __syncthreads();
  // exclusive scan of hist over 512 bins
  u32 v = hist[t];
  scan_tmp[t] = v;
  __syncthreads();
  for (int o = 1; o < 512; o <<= 1) {
    u32 x = (t >= o) ? scan_tmp[t - o] : 0;
    __syncthreads();
    scan_tmp[t] += x;
    __syncthreads();
  }
  hbase[t] = scan_tmp[t] - v;
  if (t < NB && v > 0) gbase[t] = atomicAdd(&cursor[t], (int)v);
  __syncthreads();
  // rank within (tile,bucket) and stage in bucket-sorted order
#pragma unroll
  for (int j = 0; j < MS_EPT; ++j) {
    if (myb[j] >= 0) {
      u32 rk = atomicAdd(&rankc[myb[j]], 1u);
      stage[hbase[myb[j]] + rk].x = mycv[j];
      stage[hbase[myb[j]] + rk].y = myrow[j];
    }
  }
  __syncthreads();
  int cnt = E - tile0;
  cnt = cnt < MS_TILE ? cnt : MS_TILE;
  for (int k = t; k < cnt; k += 512) {
    uint2 rec = stage[k];
    int b = (int)(rec.y >> BSHIFT);
    int off = gbase[b] + (k - (int)hbase[b]);
    if (off < cap) recs[(size_t)b * cap + off] = rec;
  }
}

// Per-bucket CSR: row-sort the bucket's records in LDS, write coalesced 4B records
// plus per-row start/count. One block per bucket.
__global__ __launch_bounds__(512) void bucket_csr(const uint2* __restrict__ recs,
                                                  const int* __restrict__ cursor,
                                                  u32* __restrict__ recs2,
                                                  int* __restrict__ rowstart,
                                                  int* __restrict__ rowcnt, int n, int cap) {
  __shared__ int hist[BROWS];
  __shared__ int sc[BROWS];
  __shared__ int hbase[BROWS];
  __shared__ u32 rank[BROWS];
  __shared__ u32 stage[STAGE_CAP];
  const int t = threadIdx.x;
  const int b = blockIdx.x;
  int cnt = cursor[b];
  cnt = cnt < cap ? cnt : cap;
  const uint2* rb = recs + (size_t)b * cap;
  if (t < BROWS) { hist[t] = 0; rank[t] = 0; }
  __syncthreads();
  for (int i = t; i < cnt; i += 512) atomicAdd(&hist[rb[i].y & (BROWS - 1)], 1);
  __syncthreads();
  if (t < BROWS) sc[t] = hist[t];
  __syncthreads();
  for (int o = 1; o < BROWS; o <<= 1) {
    int x = (t >= o && t < BROWS) ? sc[t - o] : 0;
    __syncthreads();
    if (t < BROWS) sc[t] += x;
    __syncthreads();
  }
  if (t < BROWS) {
    hbase[t] = sc[t] - hist[t];
    int r = (b << BSHIFT) + t;
    if (r < n) {
      rowstart[r] = b * cap + hbase[t];
      rowcnt[r] = hist[t];
    }
  }
  __syncthreads();
  for (int i = t; i < cnt; i += 512) {
    uint2 rec = rb[i];
    int lr = (int)(rec.y & (BROWS - 1));
    u32 p = atomicAdd(&rank[lr], 1u);
    stage[hbase[lr] + p] = rec.x;
  }
  __syncthreads();
  u32* ob = recs2 + (size_t)b * cap;
  for (int i = t; i < cnt; i += 512) ob[i] = stage[i];
}

// wave per row; half-wave edge pairing: lanes 0-31 even edges, 32-63 odd edges.
// Each lane gathers 8B (4 bf16) of the 256B row -> one instruction covers 2 edges;
// 8-pair unroll = 16 edges (4KB) in flight per wave. Combine halves via shfl_xor.
__global__ void spmm_agg(const int* __restrict__ rowstart, const int* __restrict__ rowcnt,
                         const u32* __restrict__ recs2, const u16* __restrict__ xb,
                         u16* __restrict__ aggb, int n) {
  int row = blockIdx.x * 4 + (threadIdx.x >> 6);
  int lane = threadIdx.x & 63;
  if (row >= n) return;
  const int s = rowstart[row];
  const int cnt = rowcnt[row];
  const int hi = lane >> 5;
  const int l32 = lane & 31;
  float a0 = 0.f, a1 = 0.f, a2 = 0.f, a3 = 0.f;
  int j = 0;
#define SPMM_PAIR(P)                                                                   \
  {                                                                                    \
    u32 pk0 = recs2[s + j + 2 * (P)];                                                  \
    u32 pk1 = recs2[s + j + 2 * (P) + 1];                                              \
    u32 pk = hi ? pk1 : pk0;                                                           \
    uint2 xv = *(reinterpret_cast<const uint2*>(xb + (size_t)(pk >> 16) * DD) + l32);  \
    float vv = f16val(pk);                                                             \
    a0 += vv * bf2f((u16)(xv.x & 0xffffu));                                            \
    a1 += vv * bf2f((u16)(xv.x >> 16));                                                \
    a2 += vv * bf2f((u16)(xv.y & 0xffffu));                                            \
    a3 += vv * bf2f((u16)(xv.y >> 16));                                                \
  }
  for (; j + 15 < cnt; j += 16) {
    SPMM_PAIR(0) SPMM_PAIR(1) SPMM_PAIR(2) SPMM_PAIR(3)
    SPMM_PAIR(4) SPMM_PAIR(5) SPMM_PAIR(6) SPMM_PAIR(7)
  }
  for (; j + 1 < cnt; j += 2) { SPMM_PAIR(0) }
  if (j < cnt) {  // odd tail: hi half contributes 0 (address still valid)
    u32 pk0 = recs2[s + j];
    uint2 xv = *(reinterpret_cast<const uint2*>(xb + (size_t)(pk0 >> 16) * DD) + l32);
    float vv = hi ? 0.f : f16val(pk0);
    a0 += vv * bf2f((u16)(xv.x & 0xffffu));
    a1 += vv * bf2f((u16)(xv.x >> 16));
    a2 += vv * bf2f((u16)(xv.y & 0xffffu));
    a3 += vv * bf2f((u16)(xv.y >> 16));
  }
#undef SPMM_PAIR
  a0 += __shfl_xor(a0, 32, 64);
  a1 += __shfl_xor(a1, 32, 64);
  a2 += __shfl_xor(a2, 32, 64);
  a3 += __shfl_xor(a3, 32, 64);
  if (!hi) {
    uint2 o;
    o.x = ((u32)f2bf(a1) << 16) | (u32)f2bf(a0);
    o.y = ((u32)f2bf(a3) << 16) | (u32)f2bf(a2);
    *reinterpret_cast<uint2*>(aggb + (size_t)row * DD + l32 * 4) = o;
  }
}

// Fused 2-layer MLP, column-split: block = 32 rows, 4 waves as (m,c).
// __launch_bounds__(256,4): allow up to 128 VGPR so the compiler keeps all
// B-fragment loads of a phase in flight (load-pipelining, the r11 lesson).
// ASRC 0: A is fp32; ASRC 1: A is bf16.
template <int ASRC>
__global__ __launch_bounds__(256, 4) void mlp_fused(const void* __restrict__ Ain,
                                                    const u16* __restrict__ W1p,
                                                    const float* __restrict__ b1,
                                                    const u16* __restrict__ W2p,
                                                    const float* __restrict__ b2,
                                                    u16* __restrict__ outB, int n) {
  __shared__ u16 sm[32][136];
  const int lane = threadIdx.x & 63;
  const int wid = threadIdx.x >> 6;
  const int m = wid >> 1, c = wid & 1;
  const int row0 = blockIdx.x * 32 + m * 16;
  const int ar = lane & 15, ak = (lane >> 4) * 8;
  const int crow = 4 * (lane >> 4), ccol = lane & 15;

  f32x4 acc[4];
#pragma unroll
  for (int t = 0; t < 4; ++t) acc[t] = f32x4{0.f, 0.f, 0.f, 0.f};

#pragma unroll
  for (int ks = 0; ks < 4; ++ks) {
    short8 a;
    int r = row0 + ar;
    r = r < n ? r : n - 1;
    if (ASRC == 0) {
      const float* Ap = (const float*)Ain + (size_t)r * DD + ks * 32 + ak;
      float4 f0 = *reinterpret_cast<const float4*>(Ap);
      float4 f1 = *reinterpret_cast<const float4*>(Ap + 4);
      short8 tv;
      tv[0] = (short)f2bf(f0.x); tv[1] = (short)f2bf(f0.y);
      tv[2] = (short)f2bf(f0.z); tv[3] = (short)f2bf(f0.w);
      tv[4] = (short)f2bf(f1.x); tv[5] = (short)f2bf(f1.y);
      tv[6] = (short)f2bf(f1.z); tv[7] = (short)f2bf(f1.w);
      a = tv;
    } else {
      a = *reinterpret_cast<const short8*>((const u16*)Ain + (size_t)r * DD + ks * 32 + ak);
    }
#pragma unroll
    for (int nt4 = 0; nt4 < 4; ++nt4) {
      int nt = c * 4 + nt4;
      short8 bfr = *reinterpret_cast<const short8*>(W1p + (((ks * 8 + nt) * 64 + lane) * 8));
      acc[nt4] = __builtin_amdgcn_mfma_f32_16x16x32_bf16(a, bfr, acc[nt4], 0, 0, 0);
    }
  }
  // epilogue 1: bias + relu -> LDS (block tile, wave-disjoint quadrant)
#pragma unroll
  for (int nt4 = 0; nt4 < 4; ++nt4) {
    int col = (c * 4 + nt4) * 16 + ccol;
    float bsv = b1[col];
#pragma unroll
    for (int e = 0; e < 4; ++e) {
      float v = acc[nt4][e] + bsv;
      v = v > 0.f ? v : 0.f;
      sm[m * 16 + crow + e][col] = f2bf(v);
    }
  }
  __syncthreads();

  // GEMM2 from LDS (full K = 128 across both col-halves)
  f32x4 acc2[4];
#pragma unroll
  for (int t = 0; t < 4; ++t) acc2[t] = f32x4{0.f, 0.f, 0.f, 0.f};
#pragma unroll
  for (int ks = 0; ks < 4; ++ks) {
    short8 a2 = *reinterpret_cast<const short8*>(&sm[m * 16 + ar][ks * 32 + ak]);
#pragma unroll
    for (int nt4 = 0; nt4 < 4; ++nt4) {
      int nt = c * 4 + nt4;
      short8 bfr = *reinterpret_cast<const short8*>(W2p + (((ks * 8 + nt) * 64 + lane) * 8));
      acc2[nt4] = __builtin_amdgcn_mfma_f32_16x16x32_bf16(a2, bfr, acc2[nt4], 0, 0, 0);
    }
  }
#pragma unroll
  for (int nt4 = 0; nt4 < 4; ++nt4) {
    int col = (c * 4 + nt4) * 16 + ccol;
    float bsv = b2[col];
#pragma unroll
    for (int e = 0; e < 4; ++e) {
      int r = row0 + crow + e;
      if (r < n) outB[(size_t)r * DD + col] = f2bf(acc2[nt4][e] + bsv);
    }
  }
}

// Fully fused second-MLP + gates + final (out never touches HBM):
//   t2  = relu(agg@W3+b3)          -> LDS
//   out = t2@W4+b4                 -> LDS (bf16)
//   z   = sig(out@Wu1 + x@Wu2 + b); r = sig(out@Wr1 + x@Wr2 + b)
//   oi  = (out@Wo1 + bo1) + (r*x)@Wo2 + bo2   (rx via LDS)
//   result = (1-z)*x + z*tanh(oi)  -> fp32 d_out
// __launch_bounds__(256,4): 128-VGPR budget for load pipelining; x kept in regs
// between epilogue-1 and the final epilogue.
__global__ __launch_bounds__(256, 4) void mlp2_gates_final(
    const u16* __restrict__ Agg, const u16* __restrict__ Ax, const u16* __restrict__ W3p,
    const float* __restrict__ b3, const u16* __restrict__ W4p, const float* __restrict__ b4,
    const u16* __restrict__ Wu1p, const u16* __restrict__ Wu2p, const u16* __restrict__ Wr1p,
    const u16* __restrict__ Wr2p, const u16* __restrict__ Wo1p, const u16* __restrict__ Wo2p,
    const float* __restrict__ bu1, const float* __restrict__ bu2, const float* __restrict__ br1,
    const float* __restrict__ br2, const float* __restrict__ bo1, const float* __restrict__ bo2,
    float* __restrict__ out, int n) {
  __shared__ u16 sm[32][136];  // reused: t2 tile -> out tile -> rx tile
  const int lane = threadIdx.x & 63;
  const int wid = threadIdx.x >> 6;
  const int m = wid >> 1, c = wid & 1;
  const int row0 = blockIdx.x * 32 + m * 16;
  const int ar = lane & 15, ak = (lane >> 4) * 8;
  const int crow = 4 * (lane >> 4), ccol = lane & 15;

  // phase 1: t2 = relu(agg@W3 + b3) -> sm
  f32x4 acc[4];
#pragma unroll
  for (int t = 0; t < 4; ++t) acc[t] = f32x4{0.f, 0.f, 0.f, 0.f};
#pragma unroll
  for (int ks = 0; ks < 4; ++ks) {
    int r = row0 + ar;
    r = r < n ? r : n - 1;
    short8 a = *reinterpret_cast<const short8*>(Agg + (size_t)r * DD + ks * 32 + ak);
#pragma unroll
    for (int nt4 = 0; nt4 < 4; ++nt4) {
      int nt = c * 4 + nt4;
      short8 bfr = *reinterpret_cast<const short8*>(W3p + (((ks * 8 + nt) * 64 + lane) * 8));
      acc[nt4] = __builtin_amdgcn_mfma_f32_16x16x32_bf16(a, bfr, acc[nt4], 0, 0, 0);
    }
  }
#pragma unroll
  for (int nt4 = 0; nt4 < 4; ++nt4) {
    int col = (c * 4 + nt4) * 16 + ccol;
    float bsv = b3[col];
#pragma unroll
    for (int e = 0; e < 4; ++e) {
      float v = acc[nt4][e] + bsv;
      v = v > 0.f ? v : 0.f;
      sm[m * 16 + crow + e][col] = f2bf(v);
    }
  }
  __syncthreads();

  // phase 2: out = t2@W4 + b4 (keep in regs)
#pragma unroll
  for (int t = 0; t < 4; ++t) acc[t] = f32x4{0.f, 0.f, 0.f, 0.f};
#pragma unroll
  for (int ks = 0; ks < 4; ++ks) {
    short8 a2 = *reinterpret_cast<const short8*>(&sm[m * 16 + ar][ks * 32 + ak]);
#pragma unroll
    for (int nt4 = 0; nt4 < 4; ++nt4) {
      int nt = c * 4 + nt4;
      short8 bfr = *reinterpret_cast<const short8*>(W4p + (((ks * 8 + nt) * 64 + lane) * 8));
      acc[nt4] = __builtin_amdgcn_mfma_f32_16x16x32_bf16(a2, bfr, acc[nt4], 0, 0, 0);
    }
  }
  __syncthreads();  // all waves done reading t2 before overwriting sm
  // store out tile (bf16) -> sm
#pragma unroll
  for (int nt4 = 0; nt4 < 4; ++nt4) {
    int col = (c * 4 + nt4) * 16 + ccol;
    float bsv = b4[col];
#pragma unroll
    for (int e = 0; e < 4; ++e)
      sm[m * 16 + crow + e][col] = f2bf(acc[nt4][e] + bsv);
  }
  __syncthreads();

  // phase 3: gates. A-operands: out from LDS, x from global.
  f32x4 aZ[4], aR[4], aO[4];
#pragma unroll
  for (int t = 0; t < 4; ++t) {
    aZ[t] = f32x4{0.f, 0.f, 0.f, 0.f};
    aR[t] = f32x4{0.f, 0.f, 0.f, 0.f};
    aO[t] = f32x4{0.f, 0.f, 0.f, 0.f};
  }
#pragma unroll
  for (int ks = 0; ks < 4; ++ks) {
    int r = row0 + ar;
    r = r < n ? r : n - 1;
    short8 ao = *reinterpret_cast<const short8*>(&sm[m * 16 + ar][ks * 32 + ak]);
    short8 ax = *reinterpret_cast<const short8*>(Ax + (size_t)r * DD + ks * 32 + ak);
#pragma unroll
    for (int nt4 = 0; nt4 < 4; ++nt4) {
      int nt = c * 4 + nt4;
      size_t bo = (size_t)(((ks * 8 + nt) * 64 + lane) * 8);
      short8 b1 = *reinterpret_cast<const short8*>(Wu1p + bo);
      short8 b2 = *reinterpret_cast<const short8*>(Wu2p + bo);
      short8 b3f = *reinterpret_cast<const short8*>(Wr1p + bo);
      short8 b4f = *reinterpret_cast<const short8*>(Wr2p + bo);
      short8 b5 = *reinterpret_cast<const short8*>(Wo1p + bo);
      aZ[nt4] = __builtin_amdgcn_mfma_f32_16x16x32_bf16(ao, b1, aZ[nt4], 0, 0, 0);
      aZ[nt4] = __builtin_amdgcn_mfma_f32_16x16x32_bf16(ax, b2, aZ[nt4], 0, 0, 0);
      aR[nt4] = __builtin_amdgcn_mfma_f32_16x16x32_bf16(ao, b3f, aR[nt4], 0, 0, 0);
      aR[nt4] = __builtin_amdgcn_mfma_f32_16x16x32_bf16(ax, b4f, aR[nt4], 0, 0, 0);
      aO[nt4] = __builtin_amdgcn_mfma_f32_16x16x32_bf16(ao, b5, aO[nt4], 0, 0, 0);
    }
  }
  __syncthreads();  // done reading out tile before overwriting sm with rx
  // epilogue: z (keep f32 in aZ), oi1 (fold bias into aO), rx -> sm; x -> regs
  f32x4 xsave[4];
#pragma unroll
  for (int nt4 = 0; nt4 < 4; ++nt4) {
    int col = (c * 4 + nt4) * 16 + ccol;
    float bz = bu1[col] + bu2[col];
    float br_ = br1[col] + br2[col];
    float bo_ = bo1[col];
#pragma unroll
    for (int e = 0; e < 4; ++e) {
      int r = row0 + crow + e;
      float z = sigmoidf_(aZ[nt4][e] + bz);
      float rr = sigmoidf_(aR[nt4][e] + br_);
      aZ[nt4][e] = z;
      aO[nt4][e] = aO[nt4][e] + bo_;
      float xv = 0.f;
      if (r < n) xv = bf2f(Ax[(size_t)r * DD + col]);
      xsave[nt4][e] = xv;
      sm[m * 16 + crow + e][col] = f2bf(rr * xv);
    }
  }
  __syncthreads();

  // phase 4: rx@Wo2 from LDS, final epilogue -> fp32 out
  f32x4 acc2[4];
#pragma unroll
  for (int t = 0; t < 4; ++t) acc2[t] = f32x4{0.f, 0.f, 0.f, 0.f};
#pragma unroll
  for (int ks = 0; ks < 4; ++ks) {
    short8 a2 = *reinterpret_cast<const short8*>(&sm[m * 16 + ar][ks * 32 + ak]);
#pragma unroll
    for (int nt4 = 0; nt4 < 4; ++nt4) {
      int nt = c * 4 + nt4;
      short8 bfr = *reinterpret_cast<const short8*>(Wo2p + (((ks * 8 + nt) * 64 + lane) * 8));
      acc2[nt4] = __builtin_amdgcn_mfma_f32_16x16x32_bf16(a2, bfr, acc2[nt4], 0, 0, 0);
    }
  }
#pragma unroll
  for (int nt4 = 0; nt4 < 4; ++nt4) {
    int col = (c * 4 + nt4) * 16 + ccol;
    float bo2v = bo2[col];
#pragma unroll
    for (int e = 0; e < 4; ++e) {
      int r = row0 + crow + e;
      if (r < n) {
        size_t idx = (size_t)r * DD + col;
        float oi = acc2[nt4][e] + bo2v + aO[nt4][e];
        float h = tanhf_(oi);
        float z = aZ[nt4][e];
        out[idx] = (1.f - z) * xsave[nt4][e] + z * h;
      }
    }
  }
}

extern "C" void kernel_launch(void* const* d_in, const int* in_sizes, int n_in,
                              void* d_out, int out_size, void* d_ws, size_t ws_size,
                              hipStream_t stream) {
  const int n = in_sizes[0] / DD;  // 50000
  const int E = in_sizes[1];       // 1.6M
  const float* x_in = (const float*)d_in[0];
  const int* rows = (const int*)d_in[1];
  const int* cols = (const int*)d_in[2];
  const float* vals = (const float*)d_in[3];
  const float* Wm[10];
  const float* Bm[10];
  for (int i = 0; i < 10; ++i) {
    Wm[i] = (const float*)d_in[4 + 2 * i];
    Bm[i] = (const float*)d_in[5 + 2 * i];
  }

  const int NB = (n + BROWS - 1) >> BSHIFT;           // 391
  int cap = (((E / NB) * 5) / 4 + 511) & ~511;        // ~5120, 16-sigma slack
  cap = cap < STAGE_CAP ? cap : STAGE_CAP;

  char* base = (char*)d_ws;
  size_t off = 0;
  auto alloc = [&](size_t bytes) -> char* {
    char* p = base + off;
    off += (bytes + 255) & ~(size_t)255;
    return p;
  };
  u16* wpack = (u16*)alloc((size_t)10 * 16384 * 2);
  u16* x_b = (u16*)alloc((size_t)n * DD * 2);
  u16* agg_b = (u16*)alloc((size_t)n * DD * 2);
  int* cursor = (int*)alloc((size_t)NB * 4);
  int* rowstart = (int*)alloc((size_t)n * 4);
  int* rowcnt = (int*)alloc((size_t)n * 4);
  uint2* recs = (uint2*)alloc((size_t)NB * cap * 8);
  u32* recs2 = (u32*)alloc((size_t)NB * cap * 4);
  (void)ws_size;
  (void)n_in;
  (void)out_size;

  hipMemsetAsync(cursor, 0, (size_t)NB * 4, stream);
  WPtrs wp;
  for (int i = 0; i < 10; ++i) wp.w[i] = Wm[i];
  pack_weights<<<10, 256, 0, stream>>>(wp, wpack);
  // bucket the edges (coalesced writes)
  multisplit<<<(E + MS_TILE - 1) / MS_TILE, 512, 0, stream>>>(rows, cols, vals, cursor, recs, E,
                                                             NB, cap);
  // row-sort each bucket in LDS -> per-row CSR with coalesced writes
  bucket_csr<<<NB, 512, 0, stream>>>(recs, cursor, recs2, rowstart, rowcnt, n, cap);
  int gblocks = (n + 31) / 32;  // 1563 blocks
  // x = mlp2(x_in, m1_*)  (fp32 input, fused 2-layer)
  mlp_fused<0><<<gblocks, 256, 0, stream>>>(x_in, wpack + 0 * 16384, Bm[0], wpack + 1 * 16384,
                                            Bm[1], x_b, n);
  // agg = segment_sum(vals * x[cols], rows)  (half-wave paired gather)
  spmm_agg<<<(n + 3) / 4, 256, 0, stream>>>(rowstart, rowcnt, recs2, x_b, agg_b, n);
  // out-MLP + gates + final fully fused (out never hits HBM)
  mlp2_gates_final<<<gblocks, 256, 0, stream>>>(
      agg_b, x_b, wpack + 2 * 16384, Bm[2], wpack + 3 * 16384, Bm[3], wpack + 4 * 16384,
      wpack + 5 * 16384, wpack + 6 * 16384, wpack + 7 * 16384, wpack + 8 * 16384,
      wpack + 9 * 16384, Bm[4], Bm[5], Bm[6], Bm[7], Bm[8], Bm[9], (float*)d_out, n);
}